// Round 3
// baseline (731.347 us; speedup 1.0000x reference)
//
#include <hip/hip_runtime.h>
#include <math.h>

#define E_ 8
#define H_ 256
#define N_ 65536
#define NHID_ 3
#define MT 64          // points per workgroup tile
#define HPAD 264       // LDS row stride (bf16 elems), +8 pad
#define OMEGA_ 30.0f

typedef __attribute__((ext_vector_type(8))) __bf16 bf16x8;
typedef __attribute__((ext_vector_type(4))) float f32x4;

// split v into bf16 hi + bf16 lo (double-bf16, ~17-18 effective mantissa bits)
__device__ __forceinline__ void split_bf16(float v, __bf16& hi, __bf16& lo) {
  hi = (__bf16)v;
  lo = (__bf16)(v - (float)hi);
}

// ---- zero d_out (harness poisons it with 0xAA; we accumulate atomically) ----
__global__ void zero_out_k(float* __restrict__ out) {
  out[blockIdx.x * 256 + threadIdx.x] = 0.0f;   // grid exactly N_*3/256
}

// ---- fused MoE-SIREN: one WG = (expert e, 64-point tile). NO workspace. ----
__global__ __launch_bounds__(256) void moe_main_k(
    const float* __restrict__ x,
    const float* __restrict__ gate_W,
    const float* __restrict__ gate_b,
    const float* __restrict__ W0,
    const float* __restrict__ b0,
    const float* __restrict__ Wh,
    const float* __restrict__ bh,
    const float* __restrict__ Wout,
    const float* __restrict__ bout,
    float* __restrict__ out)
{
  __shared__ alignas(16) __bf16 h_hi[MT * HPAD];   // 33792 B
  __shared__ alignas(16) __bf16 h_lo[MT * HPAD];   // 33792 B
  __shared__ float gate_s[MT];

  const int e    = blockIdx.y;
  const int m0   = blockIdx.x * MT;
  const int tid  = threadIdx.x;
  const int wave = tid >> 6;
  const int lane = tid & 63;
  const int l15  = lane & 15;
  const int quad = lane >> 4;

  // gate for this expert, one row per thread (fp32, matches jax softmax)
  if (tid < MT) {
    const int mg = m0 + tid;
    const float x0 = x[mg * 2 + 0];
    const float x1 = x[mg * 2 + 1];
    float lg[E_];
    float mx = -1e30f;
#pragma unroll
    for (int k = 0; k < E_; ++k) {
      lg[k] = x0 * gate_W[k] + x1 * gate_W[E_ + k] + gate_b[k];
      mx = fmaxf(mx, lg[k]);
    }
    float s = 0.0f;
#pragma unroll
    for (int k = 0; k < E_; ++k) s += __expf(lg[k] - mx);
    gate_s[tid] = __expf(lg[e] - mx) / s;
  }

  // first sine layer in fp32; thread tid owns column n=tid for all 64 rows.
  {
    const float w0a = W0[(e * 2 + 0) * H_ + tid];
    const float w1a = W0[(e * 2 + 1) * H_ + tid];
    const float bb  = b0[e * H_ + tid];
    for (int m = 0; m < MT; ++m) {
      const float x0 = x[(m0 + m) * 2 + 0];   // wave-uniform
      const float x1 = x[(m0 + m) * 2 + 1];
      const float z = OMEGA_ * fmaf(x1, w1a, fmaf(x0, w0a, bb));
      const float h = __sinf(z);
      __bf16 hi, lo; split_bf16(h, hi, lo);
      h_hi[m * HPAD + tid] = hi;
      h_lo[m * HPAD + tid] = lo;
    }
  }
  __syncthreads();

  // 3 hidden layers, split-bf16 MFMA (3 products). Wave w owns n-cols [w*64, w*64+64).
  // B-fragments loaded DIRECTLY from fp32 Wh (no packing, no d_ws):
  //   B[k = kb*32 + quad*8 + j][n = nb*16 + l15], k-stride = H_ floats.
  const int nb0 = wave * 4;
#pragma unroll 1
  for (int l = 0; l < NHID_; ++l) {
    const float* WB = Wh + (size_t)(e * NHID_ + l) * (H_ * H_);
    f32x4 acc[4][4];
#pragma unroll
    for (int mt = 0; mt < 4; ++mt)
#pragma unroll
      for (int nbi = 0; nbi < 4; ++nbi)
        acc[mt][nbi] = (f32x4){0.f, 0.f, 0.f, 0.f};

#pragma unroll 2
    for (int kb = 0; kb < 8; ++kb) {
      const int k0 = kb * 32 + quad * 8;
      // issue all 32 B-loads first (vmcnt overlaps the LDS reads below)
      float bfv[4][8];
#pragma unroll
      for (int nbi = 0; nbi < 4; ++nbi) {
        const float* p = WB + (size_t)k0 * H_ + (nb0 + nbi) * 16 + l15;
#pragma unroll
        for (int j = 0; j < 8; ++j) bfv[nbi][j] = p[(size_t)j * H_];
      }
      // A-fragments from LDS
      bf16x8 ah[4], al[4];
#pragma unroll
      for (int mt = 0; mt < 4; ++mt) {
        ah[mt] = *reinterpret_cast<const bf16x8*>(&h_hi[(mt * 16 + l15) * HPAD + k0]);
        al[mt] = *reinterpret_cast<const bf16x8*>(&h_lo[(mt * 16 + l15) * HPAD + k0]);
      }
      // split B to hi/lo fragments
      bf16x8 bhf[4], blf[4];
#pragma unroll
      for (int nbi = 0; nbi < 4; ++nbi)
#pragma unroll
        for (int j = 0; j < 8; ++j) {
          __bf16 hi, lo; split_bf16(bfv[nbi][j], hi, lo);
          bhf[nbi][j] = hi; blf[nbi][j] = lo;
        }
#pragma unroll
      for (int mt = 0; mt < 4; ++mt)
#pragma unroll
        for (int nbi = 0; nbi < 4; ++nbi) {
          f32x4 a = acc[mt][nbi];
          a = __builtin_amdgcn_mfma_f32_16x16x32_bf16(al[mt], bhf[nbi], a, 0, 0, 0);
          a = __builtin_amdgcn_mfma_f32_16x16x32_bf16(ah[mt], blf[nbi], a, 0, 0, 0);
          a = __builtin_amdgcn_mfma_f32_16x16x32_bf16(ah[mt], bhf[nbi], a, 0, 0, 0);
          acc[mt][nbi] = a;
        }
    }
    __syncthreads();   // all reads of h done before any rewrite

    const float* bhrow = bh + (size_t)(e * NHID_ + l) * H_;
#pragma unroll
    for (int nbi = 0; nbi < 4; ++nbi) {
      const int n = (nb0 + nbi) * 16 + l15;         // D col = lane&15
      const float bias = bhrow[n];
#pragma unroll
      for (int mt = 0; mt < 4; ++mt) {
        const int rbase = mt * 16 + quad * 4;       // D row = quad*4+i
#pragma unroll
        for (int i = 0; i < 4; ++i) {
          const float z = OMEGA_ * (acc[mt][nbi][i] + bias);
          const float h = __sinf(z);
          __bf16 hi, lo; split_bf16(h, hi, lo);
          h_hi[(rbase + i) * HPAD + n] = hi;
          h_lo[(rbase + i) * HPAD + n] = lo;
        }
      }
    }
    __syncthreads();
  }

  // output layer: wave w owns rows [w*16, w*16+16); 3 cols padded to 16.
  {
    const float* WO = Wout + (size_t)e * (H_ * 3);
    f32x4 acco = (f32x4){0.f, 0.f, 0.f, 0.f};
    const int arow = wave * 16 + l15;
#pragma unroll
    for (int kb = 0; kb < 8; ++kb) {
      const int k0 = kb * 32 + quad * 8;
      float bfv[8];
#pragma unroll
      for (int j = 0; j < 8; ++j)
        bfv[j] = (l15 < 3) ? WO[(size_t)(k0 + j) * 3 + l15] : 0.0f;
      bf16x8 ah = *reinterpret_cast<const bf16x8*>(&h_hi[arow * HPAD + k0]);
      bf16x8 al = *reinterpret_cast<const bf16x8*>(&h_lo[arow * HPAD + k0]);
      bf16x8 bhf, blf;
#pragma unroll
      for (int j = 0; j < 8; ++j) {
        __bf16 hi, lo; split_bf16(bfv[j], hi, lo);
        bhf[j] = hi; blf[j] = lo;
      }
      acco = __builtin_amdgcn_mfma_f32_16x16x32_bf16(al, bhf, acco, 0, 0, 0);
      acco = __builtin_amdgcn_mfma_f32_16x16x32_bf16(ah, blf, acco, 0, 0, 0);
      acco = __builtin_amdgcn_mfma_f32_16x16x32_bf16(ah, bhf, acco, 0, 0, 0);
    }
    const int c = l15;
    if (c < 3) {
      const float bo = bout[e * 3 + c];
      const int rb = wave * 16 + quad * 4;
#pragma unroll
      for (int i = 0; i < 4; ++i) {
        const int m = rb + i;
        const float val = gate_s[m] * (acco[i] + bo);
        atomicAdd(&out[(size_t)(m0 + m) * 3 + c], val);
      }
    }
  }
}

extern "C" void kernel_launch(void* const* d_in, const int* in_sizes, int n_in,
                              void* d_out, int out_size, void* d_ws, size_t ws_size,
                              hipStream_t stream) {
  const float* x     = (const float*)d_in[0];
  const float* gateW = (const float*)d_in[1];
  const float* gateb = (const float*)d_in[2];
  const float* W0    = (const float*)d_in[3];
  const float* b0    = (const float*)d_in[4];
  const float* Wh    = (const float*)d_in[5];
  const float* bh    = (const float*)d_in[6];
  const float* Wout  = (const float*)d_in[7];
  const float* bout  = (const float*)d_in[8];
  float* out = (float*)d_out;
  (void)d_ws; (void)ws_size;   // deliberately unused this round (ws-overflow probe)

  hipLaunchKernelGGL(zero_out_k, dim3(N_ * 3 / 256), dim3(256), 0, stream, out);
  hipLaunchKernelGGL(moe_main_k, dim3(N_ / MT, E_), dim3(256), 0, stream,
                     x, gateW, gateb, W0, b0, Wh, bh, Wout, bout, out);
}